// Round 1
// baseline (348.959 us; speedup 1.0000x reference)
//
#include <hip/hip_runtime.h>
#include <hip/hip_bf16.h>

// Problem constants
#define B_SZ 256
#define IMG 88
#define CIN 3
#define NCH 64
#define OP 11           // output positions per dim
#define NPOS 121        // 11*11
#define KWIN 8          // conv window & stride
#define KVOL 192        // 8*8*3

// ---------------------------------------------------------------------------
// Kernel 1: int->float normalize + 8x8 stride-8 VALID conv + bias + relu
// grid = B*11 (one block per (batch, oy) row), block = 256
// Wave lanes = 64 channels of one ox position -> coalesced weight loads,
// LDS-broadcast patch reads.
// ---------------------------------------------------------------------------
__global__ __launch_bounds__(256) void conv_kernel(
    const int* __restrict__ rgb, const float* __restrict__ Wc,
    const float* __restrict__ bc, float* __restrict__ out) {
  const int b  = blockIdx.x / OP;
  const int oy = blockIdx.x % OP;

  __shared__ float strip[KWIN * IMG * CIN];  // 2112 floats, [ky][x][ci]

  const int* src = rgb + (size_t)(b * IMG + oy * KWIN) * IMG * CIN;
  for (int i = threadIdx.x; i < KWIN * IMG * CIN; i += 256) {
    strip[i] = (float)src[i] * (1.0f / 255.0f);
  }
  __syncthreads();

  // 704 outputs per block: idx = pos*64 + ch ; pos (=ox) is wave-uniform
  for (int idx = threadIdx.x; idx < OP * NCH; idx += 256) {
    const int pos = idx >> 6;   // ox
    const int ch  = idx & 63;
    float acc = bc[ch];
    #pragma unroll
    for (int ky = 0; ky < KWIN; ++ky) {
      #pragma unroll
      for (int kx = 0; kx < KWIN; ++kx) {
        #pragma unroll
        for (int ci = 0; ci < CIN; ++ci) {
          const float x = strip[(ky * IMG + pos * KWIN + kx) * CIN + ci];
          const float w = Wc[((ky * KWIN + kx) * CIN + ci) * NCH + ch];
          acc = fmaf(x, w, acc);
        }
      }
    }
    acc = fmaxf(acc, 0.0f);
    out[((size_t)(b * NPOS + oy * OP + pos)) * NCH + ch] = acc;
  }
}

// ---------------------------------------------------------------------------
// Kernel 2: guidance from feats. One block per batch, 128 threads (2 waves).
// counts[i] = #rows exactly equal to row i; mask by cumulative-hist rule;
// softmax(-log c) == (1/c_i) / sum_allowed(1/c_j).
// ---------------------------------------------------------------------------
__global__ __launch_bounds__(128) void guide_kernel(
    const float* __restrict__ feats, float* __restrict__ gout) {
  const int b = blockIdx.x;
  const int tid = threadIdx.x;

  __shared__ float f[NPOS][NCH + 1];  // +1 pad: per-lane row reads conflict-free
  __shared__ int counts[NPOS];
  __shared__ int hist[128];           // counts range 1..121; reused as allow[]
  __shared__ float wsum[2];

  const float* src = feats + (size_t)b * NPOS * NCH;
  for (int i = tid; i < NPOS * NCH; i += 128) {
    f[i >> 6][i & 63] = src[i];
  }
  hist[tid] = 0;
  __syncthreads();

  if (tid < NPOS) {
    int cnt = 0;
    for (int j = 0; j < NPOS; ++j) {
      bool eq = true;
      for (int c = 0; c < NCH; ++c) {
        if (f[tid][c] != f[j][c]) { eq = false; break; }
      }
      cnt += eq ? 1 : 0;
    }
    counts[tid] = cnt;
    atomicAdd(&hist[cnt], 1);
  }
  __syncthreads();

  if (tid == 0) {
    int kmin = 1 << 30;
    for (int i = 0; i < NPOS; ++i) kmin = min(kmin, counts[i]);
    const int K = (int)(0.3f * NPOS);  // 36
    int cum = 0;
    for (int k = 0; k <= NPOS; ++k) {
      cum += hist[k];
      hist[k] = ((cum <= K) || (k == kmin)) ? 1 : 0;  // reuse hist as allow[]
    }
  }
  __syncthreads();

  float w = 0.0f;
  if (tid < NPOS) {
    const int c = counts[tid];
    if (hist[c]) w = 1.0f / (float)c;
  }
  // block-reduce sum (2 waves)
  float s = w;
  #pragma unroll
  for (int off = 1; off < 64; off <<= 1) s += __shfl_xor(s, off, 64);
  if ((tid & 63) == 0) wsum[tid >> 6] = s;
  __syncthreads();
  const float Z = wsum[0] + wsum[1];
  if (tid < NPOS) gout[(size_t)b * NPOS + tid] = w / Z;
}

extern "C" void kernel_launch(void* const* d_in, const int* in_sizes, int n_in,
                              void* d_out, int out_size, void* d_ws, size_t ws_size,
                              hipStream_t stream) {
  const int*   rgb = (const int*)d_in[0];
  const float* Wc  = (const float*)d_in[1];
  const float* bc  = (const float*)d_in[2];
  float* out   = (float*)d_out;                       // vis_op: 256*121*64
  float* guide = out + (size_t)B_SZ * NPOS * NCH;     // guidance: 256*121

  conv_kernel<<<B_SZ * OP, 256, 0, stream>>>(rgb, Wc, bc, out);
  guide_kernel<<<B_SZ, 128, 0, stream>>>(out, guide);
}

// Round 2
// 86.200 us; speedup vs baseline: 4.0482x; 4.0482x over previous
//
#include <hip/hip_runtime.h>
#include <hip/hip_bf16.h>

#define B_SZ 256
#define NCH 64
#define NPOS 121
#define NPATCH (B_SZ * NPOS)      // 30976
#define KTOT 192
#define MTILE 64
#define NBLK (NPATCH / MTILE)     // 484 (exact)
#define LDK 200                   // padded LDS row length in shorts (192 + 8)

typedef short bf16x8 __attribute__((ext_vector_type(8)));
typedef float f32x4 __attribute__((ext_vector_type(4)));

// round-to-nearest-even f32 -> bf16 (finite inputs)
static __device__ inline unsigned f2bf(float x) {
  union { float f; unsigned u; } a; a.f = x;
  unsigned r = a.u + 0x7FFFu + ((a.u >> 16) & 1u);
  return r >> 16;
}
static __device__ inline unsigned pack2(float lo, float hi) {
  return f2bf(lo) | (f2bf(hi) << 16);
}

// ---------------------------------------------------------------------------
// Conv as MFMA GEMM: im2col A [64 x 192] bf16 + Bt [64 x 192] bf16 in LDS,
// D = A*B, +bias, relu. One block = 64 patches, full N=64, full K=192.
// ---------------------------------------------------------------------------
__global__ __launch_bounds__(256) void conv_mfma(
    const int* __restrict__ rgb, const float* __restrict__ Wc,
    const float* __restrict__ bc, float* __restrict__ out) {
  __shared__ __align__(16) unsigned short A[MTILE * LDK];   // 25.6 KB
  __shared__ __align__(16) unsigned short Bt[NCH * LDK];    // 25.6 KB
  const int tid = threadIdx.x;
  const int blk = blockIdx.x;

  // ---- stage A: im2col, 512 strips of 24 ints (one 8x-wide row of a patch)
  for (int s = tid; s < 512; s += 256) {
    const int pl = s >> 3, ky = s & 7;
    const int P = blk * MTILE + pl;
    const int b = P / NPOS;
    const int r = P - b * NPOS;
    const int oy = r / 11;
    const int ox = r - oy * 11;
    const int4* s4 = (const int4*)(rgb + (((b * 88 + oy * 8 + ky) * 88) + ox * 8) * 3);
    float v[24];
    #pragma unroll
    for (int q = 0; q < 6; ++q) {
      const int4 t = s4[q];
      v[q * 4 + 0] = (float)t.x * (1.f / 255.f);
      v[q * 4 + 1] = (float)t.y * (1.f / 255.f);
      v[q * 4 + 2] = (float)t.z * (1.f / 255.f);
      v[q * 4 + 3] = (float)t.w * (1.f / 255.f);
    }
    unsigned short* dst = &A[pl * LDK + ky * 24];
    #pragma unroll
    for (int q = 0; q < 3; ++q) {
      uint4 p;
      p.x = pack2(v[q * 8 + 0], v[q * 8 + 1]);
      p.y = pack2(v[q * 8 + 2], v[q * 8 + 3]);
      p.z = pack2(v[q * 8 + 4], v[q * 8 + 5]);
      p.w = pack2(v[q * 8 + 6], v[q * 8 + 7]);
      *(uint4*)(dst + q * 8) = p;
    }
  }

  // ---- stage B: transpose Wc[k][n] -> Bt[n][k] in bf16
  {
    const int n = tid & 63;
    const int kg = tid >> 6;                 // 0..3, k-base kg*48
    #pragma unroll
    for (int q = 0; q < 6; ++q) {
      const int k0 = kg * 48 + q * 8;
      float w[8];
      #pragma unroll
      for (int j = 0; j < 8; ++j) w[j] = Wc[(k0 + j) * NCH + n];
      uint4 p;
      p.x = pack2(w[0], w[1]); p.y = pack2(w[2], w[3]);
      p.z = pack2(w[4], w[5]); p.w = pack2(w[6], w[7]);
      *(uint4*)&Bt[n * LDK + k0] = p;
    }
  }
  __syncthreads();

  // ---- MFMA: wave (wm,wn) owns M 32 x N 32 via 2x2 frags of 16x16
  const int lane = tid & 63;
  const int w = tid >> 6;
  const int m0 = (w >> 1) * 32;
  const int n0 = (w & 1) * 32;
  const int lr = lane & 15;
  const int lg = lane >> 4;

  f32x4 acc[2][2] = {};
  #pragma unroll
  for (int ks = 0; ks < 6; ++ks) {
    const int k0 = ks * 32 + lg * 8;
    const bf16x8 a0 = *(const bf16x8*)&A[(m0 + lr) * LDK + k0];
    const bf16x8 a1 = *(const bf16x8*)&A[(m0 + 16 + lr) * LDK + k0];
    const bf16x8 b0 = *(const bf16x8*)&Bt[(n0 + lr) * LDK + k0];
    const bf16x8 b1 = *(const bf16x8*)&Bt[(n0 + 16 + lr) * LDK + k0];
    acc[0][0] = __builtin_amdgcn_mfma_f32_16x16x32_bf16(a0, b0, acc[0][0], 0, 0, 0);
    acc[0][1] = __builtin_amdgcn_mfma_f32_16x16x32_bf16(a0, b1, acc[0][1], 0, 0, 0);
    acc[1][0] = __builtin_amdgcn_mfma_f32_16x16x32_bf16(a1, b0, acc[1][0], 0, 0, 0);
    acc[1][1] = __builtin_amdgcn_mfma_f32_16x16x32_bf16(a1, b1, acc[1][1], 0, 0, 0);
  }

  // ---- epilogue: +bias, relu, store. D: col = lane&15, row = (lane>>4)*4+reg
  #pragma unroll
  for (int ni = 0; ni < 2; ++ni) {
    const int col = n0 + ni * 16 + lr;
    const float bias = bc[col];
    #pragma unroll
    for (int mi = 0; mi < 2; ++mi) {
      #pragma unroll
      for (int rr = 0; rr < 4; ++rr) {
        const int row = m0 + mi * 16 + lg * 4 + rr;
        out[(size_t)(blk * MTILE + row) * NCH + col] = fmaxf(acc[mi][ni][rr] + bias, 0.f);
      }
    }
  }
}

// ---------------------------------------------------------------------------
// Guidance: per-row bitwise signature -> branch-free count loop; exact verify
// only on signature matches beyond self (essentially never taken).
// ---------------------------------------------------------------------------
__global__ __launch_bounds__(256) void guide_kernel(
    const float* __restrict__ feats, float* __restrict__ gout) {
  const int b = blockIdx.x, tid = threadIdx.x;
  __shared__ __align__(16) unsigned f[NPOS * NCH];   // 31 KB raw bits
  __shared__ unsigned sig[NPOS];
  __shared__ int counts[NPOS];
  __shared__ int allow[NPOS + 1];                    // hist, then allow flags
  __shared__ float wsum[4];

  if (tid < NPOS) sig[tid] = 0u;
  if (tid <= NPOS) allow[tid] = 0;
  __syncthreads();

  const uint4* src = (const uint4*)(feats + (size_t)b * NPOS * NCH);
  for (int g = tid; g < NPOS * 16; g += 256) {
    const uint4 v = src[g];
    ((uint4*)f)[g] = v;
    const int row = g >> 4;
    const int k = (g & 15) * 4;
    unsigned h = 0;
    h ^= (v.x ^ (v.x >> 15)) * ((2u * (k + 0) + 1u) * 0x9E3779B9u);
    h ^= (v.y ^ (v.y >> 15)) * ((2u * (k + 1) + 1u) * 0x9E3779B9u);
    h ^= (v.z ^ (v.z >> 15)) * ((2u * (k + 2) + 1u) * 0x9E3779B9u);
    h ^= (v.w ^ (v.w >> 15)) * ((2u * (k + 3) + 1u) * 0x9E3779B9u);
    atomicXor(&sig[row], h);
  }
  __syncthreads();

  if (tid < NPOS) {
    const unsigned si = sig[tid];
    int m = 0;
    for (int j = 0; j < NPOS; ++j) m += (sig[j] == si) ? 1 : 0;
    int cnt = 1;                       // self always matches
    if (m > 1) {                       // rare: verify exactly
      cnt = 0;
      for (int j = 0; j < NPOS; ++j) {
        if (sig[j] == si) {
          int eq = 1;
          for (int c = 0; c < NCH; ++c) eq &= (f[tid * NCH + c] == f[j * NCH + c]);
          cnt += eq;
        }
      }
    }
    counts[tid] = cnt;
    atomicAdd(&allow[cnt], 1);
  }
  __syncthreads();

  if (tid == 0) {
    int kmin = counts[0];
    for (int i = 1; i < NPOS; ++i) kmin = min(kmin, counts[i]);
    int cum = 0;
    const int K = 36;                  // int(0.3 * 121)
    for (int k = 0; k <= NPOS; ++k) {
      cum += allow[k];
      allow[k] = (cum <= K || k == kmin) ? 1 : 0;
    }
  }
  __syncthreads();

  float wv = 0.f;
  if (tid < NPOS) {
    const int c = counts[tid];
    if (allow[c]) wv = 1.f / (float)c;
  }
  float s = wv;
  #pragma unroll
  for (int off = 1; off < 64; off <<= 1) s += __shfl_xor(s, off, 64);
  if ((tid & 63) == 0) wsum[tid >> 6] = s;
  __syncthreads();
  const float Z = wsum[0] + wsum[1] + wsum[2] + wsum[3];
  if (tid < NPOS) gout[(size_t)b * NPOS + tid] = wv / Z;
}

extern "C" void kernel_launch(void* const* d_in, const int* in_sizes, int n_in,
                              void* d_out, int out_size, void* d_ws, size_t ws_size,
                              hipStream_t stream) {
  const int*   rgb = (const int*)d_in[0];
  const float* Wc  = (const float*)d_in[1];
  const float* bc  = (const float*)d_in[2];
  float* out   = (float*)d_out;                        // vis_op: 30976 x 64
  float* guide = out + (size_t)NPATCH * NCH;           // guidance: 256 x 121

  conv_mfma<<<NBLK, 256, 0, stream>>>(rgb, Wc, bc, out);
  guide_kernel<<<B_SZ, 256, 0, stream>>>(out, guide);
}

// Round 3
// 84.171 us; speedup vs baseline: 4.1458x; 1.0241x over previous
//
#include <hip/hip_runtime.h>
#include <hip/hip_bf16.h>

#define B_SZ 256
#define NCH 64
#define NPOS 121
#define NPATCH (B_SZ * NPOS)      // 30976
#define KTOT 192
#define RGB_W 264                 // 88*3 elements per image row
#define LDR 264                   // LDS row stride (shorts) for bf16 image
#define FST 68                    // feats-bits row stride (words), pad vs 64

typedef short bf16x8 __attribute__((ext_vector_type(8)));
typedef float f32x4 __attribute__((ext_vector_type(4)));

// round-to-nearest-even f32 -> bf16 (finite inputs), sign-agnostic bit trick
static __device__ inline unsigned f2bf(float x) {
  union { float f; unsigned u; } a; a.f = x;
  return (a.u + 0x7FFFu + ((a.u >> 16) & 1u)) >> 16;
}
static __device__ inline unsigned pack2(float lo, float hi) {
  return f2bf(lo) | (f2bf(hi) << 16);
}

// ---------------------------------------------------------------------------
// kernel0: pack Wc [192][64] f32 -> Btg [64][192] bf16 (n-major, 16B rows)
// ---------------------------------------------------------------------------
__global__ __launch_bounds__(256) void pack_b(const float* __restrict__ Wc,
                                              unsigned short* __restrict__ Btg) {
  const int n = threadIdx.x & 63;        // channel
  const int q = threadIdx.x >> 6;        // k-range q*48 .. q*48+47
  const int k0 = q * 48;
  float w[48];
  #pragma unroll
  for (int j = 0; j < 48; ++j) w[j] = Wc[(k0 + j) * NCH + n];  // coalesced in n
  #pragma unroll
  for (int c = 0; c < 6; ++c) {
    uint4 p;
    p.x = pack2(w[c*8+0], w[c*8+1]); p.y = pack2(w[c*8+2], w[c*8+3]);
    p.z = pack2(w[c*8+4], w[c*8+5]); p.w = pack2(w[c*8+6], w[c*8+7]);
    *(uint4*)&Btg[n * KTOT + k0 + c * 8] = p;
  }
}

// ---------------------------------------------------------------------------
// fused: conv (MFMA, no im2col) + bias + relu + guidance, one block per batch
// ---------------------------------------------------------------------------
__global__ __launch_bounds__(256) void fused(
    const int* __restrict__ rgb, const unsigned short* __restrict__ Btg,
    const float* __restrict__ bc, float* __restrict__ out,
    float* __restrict__ gout) {
  __shared__ __align__(16) unsigned short rgbL[88 * LDR];  // 46.5 KB, aliased below
  __shared__ unsigned sig[NPOS];
  __shared__ int counts[NPOS];
  __shared__ int redi[4];
  __shared__ float redf[4];
  unsigned* fbits = (unsigned*)rgbL;     // [NPOS][FST] words, 32.9 KB < 46.5 KB

  const int b = blockIdx.x, tid = threadIdx.x;
  const int lane = tid & 63, w = tid >> 6;
  const int lr = lane & 15, lg = lane >> 4;

  // ---- B fragments: 24 x bf16x8 per lane, coalesced 16B loads from L2
  bf16x8 bfr[4][6];
  #pragma unroll
  for (int ni = 0; ni < 4; ++ni)
    #pragma unroll
    for (int ks = 0; ks < 6; ++ks)
      bfr[ni][ks] = *(const bf16x8*)&Btg[(ni * 16 + lr) * KTOT + ks * 32 + lg * 8];

  // ---- stage normalized image as bf16 [88][264] (coalesced int4 reads)
  const int4* src4 = (const int4*)(rgb + (size_t)b * 88 * RGB_W);
  #pragma unroll 4
  for (int it = 0; it < 22; ++it) {      // 22*256 = 5632 of 5808 int4s
    const int i = tid + it * 256;
    const int4 t = src4[i];
    const int e = i * 4, row = e / RGB_W, col = e - row * RGB_W;
    uint2 p;
    p.x = pack2((float)t.x * (1.f/255.f), (float)t.y * (1.f/255.f));
    p.y = pack2((float)t.z * (1.f/255.f), (float)t.w * (1.f/255.f));
    *(uint2*)&rgbL[row * LDR + col] = p;
  }
  {
    const int i = tid + 5632;
    if (i < 5808) {
      const int4 t = src4[i];
      const int e = i * 4, row = e / RGB_W, col = e - row * RGB_W;
      uint2 p;
      p.x = pack2((float)t.x * (1.f/255.f), (float)t.y * (1.f/255.f));
      p.y = pack2((float)t.z * (1.f/255.f), (float)t.w * (1.f/255.f));
      *(uint2*)&rgbL[row * LDR + col] = p;
    }
  }
  __syncthreads();

  // ---- MFMA: wave w owns patch rows w*32..w*32+31, full N=64, K=192
  const int m0 = w * 32;
  f32x4 acc[2][4] = {};
  int kyv[6], kmv[6];
  #pragma unroll
  for (int ks = 0; ks < 6; ++ks) {
    const int k0 = ks * 32 + lg * 8;     // multiple of 8 -> never crosses a ky row
    kyv[ks] = k0 / 24; kmv[ks] = k0 - kyv[ks] * 24;
  }
  #pragma unroll
  for (int mi = 0; mi < 2; ++mi) {
    const int p = m0 + mi * 16 + lr;
    const int pe = p > 120 ? 120 : p;    // clamp pad rows (discarded later)
    const int oy = pe / 11, ox = pe - oy * 11;
    #pragma unroll
    for (int ks = 0; ks < 6; ++ks) {
      const bf16x8 a =
          *(const bf16x8*)&rgbL[(oy * 8 + kyv[ks]) * LDR + ox * 24 + kmv[ks]];
      #pragma unroll
      for (int ni = 0; ni < 4; ++ni)
        acc[mi][ni] = __builtin_amdgcn_mfma_f32_16x16x32_bf16(
            a, bfr[ni][ks], acc[mi][ni], 0, 0, 0);
    }
  }
  __syncthreads();                        // all rgbL reads done before aliasing

  // ---- epilogue: +bias, relu, +0 (kill -0), store global + LDS bits
  float bias[4];
  #pragma unroll
  for (int ni = 0; ni < 4; ++ni) bias[ni] = bc[ni * 16 + lr];
  float* outB = out + (size_t)b * NPOS * NCH;
  #pragma unroll
  for (int mi = 0; mi < 2; ++mi) {
    #pragma unroll
    for (int rr = 0; rr < 4; ++rr) {
      const int p = m0 + mi * 16 + lg * 4 + rr;
      if (p < NPOS) {
        #pragma unroll
        for (int ni = 0; ni < 4; ++ni) {
          const int col = ni * 16 + lr;
          const float v = fmaxf(acc[mi][ni][rr] + bias[ni], 0.f) + 0.f;
          outB[p * NCH + col] = v;
          fbits[p * FST + col] = __float_as_uint(v);
        }
      }
    }
  }
  __syncthreads();

  // ---- per-row signature (own-row hash, no atomics)
  if (tid < NPOS) {
    const uint4* fr = (const uint4*)&fbits[tid * FST];
    unsigned h = 0;
    #pragma unroll
    for (int q = 0; q < 16; ++q) {
      const uint4 v = fr[q];
      h ^= (v.x ^ (v.x >> 15)) * ((8u*q + 1u) * 0x9E3779B9u);
      h ^= (v.y ^ (v.y >> 15)) * ((8u*q + 3u) * 0x9E3779B9u);
      h ^= (v.z ^ (v.z >> 15)) * ((8u*q + 5u) * 0x9E3779B9u);
      h ^= (v.w ^ (v.w >> 15)) * ((8u*q + 7u) * 0x9E3779B9u);
    }
    sig[tid] = h;
  }
  __syncthreads();

  // ---- counts via signature match (exact verify on collision, ~never taken)
  int cnt = 0x7fffffff;
  if (tid < NPOS) {
    const unsigned si = sig[tid];
    int m = 0;
    for (int j = 0; j < NPOS; ++j) m += (sig[j] == si) ? 1 : 0;
    cnt = 1;
    if (m > 1) {
      cnt = 0;
      for (int j = 0; j < NPOS; ++j) {
        if (sig[j] == si) {
          int eq = 1;
          for (int c = 0; c < NCH; ++c) eq &= (fbits[tid*FST + c] == fbits[j*FST + c]);
          cnt += eq;
        }
      }
    }
    counts[tid] = cnt;
  }
  __syncthreads();

  // ---- kmin (block reduce)
  int km_ = cnt;
  #pragma unroll
  for (int off = 1; off < 64; off <<= 1) km_ = min(km_, __shfl_xor(km_, off, 64));
  if (lane == 0) redi[w] = km_;
  __syncthreads();
  const int kmin = min(min(redi[0], redi[1]), min(redi[2], redi[3]));

  // ---- allow rule: cum[c_i] = #{j: counts[j] <= c_i}; parallel, no histogram
  float wv = 0.f;
  if (tid < NPOS) {
    int cum = 0;
    for (int j = 0; j < NPOS; ++j) cum += (counts[j] <= cnt) ? 1 : 0;
    if (cum <= 36 || cnt == kmin) wv = 1.f / (float)cnt;   // K = int(0.3*121)
  }
  float s = wv;
  #pragma unroll
  for (int off = 1; off < 64; off <<= 1) s += __shfl_xor(s, off, 64);
  if (lane == 0) redf[w] = s;
  __syncthreads();
  const float Z = redf[0] + redf[1] + redf[2] + redf[3];
  if (tid < NPOS) gout[(size_t)b * NPOS + tid] = wv / Z;
}

extern "C" void kernel_launch(void* const* d_in, const int* in_sizes, int n_in,
                              void* d_out, int out_size, void* d_ws, size_t ws_size,
                              hipStream_t stream) {
  const int*   rgb = (const int*)d_in[0];
  const float* Wc  = (const float*)d_in[1];
  const float* bc  = (const float*)d_in[2];
  float* out   = (float*)d_out;                        // vis_op: 30976 x 64
  float* guide = out + (size_t)NPATCH * NCH;           // guidance: 256 x 121
  unsigned short* Btg = (unsigned short*)d_ws;         // 64x192 bf16 = 24.6 KB

  pack_b<<<1, 256, 0, stream>>>(Wc, Btg);
  fused<<<B_SZ, 256, 0, stream>>>(rgb, Btg, bc, out, guide);
}

// Round 4
// 78.057 us; speedup vs baseline: 4.4706x; 1.0783x over previous
//
#include <hip/hip_runtime.h>
#include <hip/hip_bf16.h>

#define B_SZ 256
#define NCH 64
#define NPOS 121
#define NPATCH (B_SZ * NPOS)      // 30976
#define KTOT 192
#define RGB_W 264                 // 88*3 ints per image row
#define LDR 264                   // LDS image row stride (shorts), 528 B
#define LDB 200                   // LDS B row stride (shorts), 400 B (16B-aligned)
#define FST 68                    // feats-bits row stride (words)

typedef short bf16x8 __attribute__((ext_vector_type(8)));
typedef float f32x4 __attribute__((ext_vector_type(4)));

// round-to-nearest-even f32 -> bf16 (finite inputs)
static __device__ inline unsigned f2bf(float x) {
  union { float f; unsigned u; } a; a.f = x;
  return (a.u + 0x7FFFu + ((a.u >> 16) & 1u)) >> 16;
}
static __device__ inline unsigned pack2(float lo, float hi) {
  return f2bf(lo) | (f2bf(hi) << 16);
}

// ---------------------------------------------------------------------------
// One block per batch, 512 threads (8 waves).
// conv (MFMA, no im2col) + bias + relu + full guidance, single launch.
// ---------------------------------------------------------------------------
__global__ __launch_bounds__(512) void fused(
    const int* __restrict__ rgb, const float* __restrict__ Wc,
    const float* __restrict__ bc, float* __restrict__ out,
    float* __restrict__ gout) {
  __shared__ __align__(16) unsigned short rgbL[88 * LDR];  // 46.5 KB (aliased later)
  __shared__ __align__(16) unsigned short BtL[NCH * LDB];  // 25.6 KB
  __shared__ unsigned sig[NPOS];
  __shared__ int counts[NPOS];
  __shared__ int redi[8];
  __shared__ float redf[8];
  unsigned* fbits = (unsigned*)rgbL;   // [NPOS][FST] words = 32.9 KB < 46.5 KB

  const int b = blockIdx.x, tid = threadIdx.x;
  const int lane = tid & 63, w = tid >> 6;   // 8 waves
  const int lr = lane & 15, lg = lane >> 4;

  // ---- B: Wc[k][n] f32 -> BtL[n][k] bf16. Wave w owns k in [w*24, w*24+24).
  // Global reads coalesced in n (lane); paired k -> one aligned b32 LDS write.
  {
    #pragma unroll
    for (int j = 0; j < 12; ++j) {
      const int k = w * 24 + 2 * j;
      const float w0 = Wc[k * NCH + lane];
      const float w1 = Wc[(k + 1) * NCH + lane];
      *(unsigned*)&BtL[lane * LDB + k] = pack2(w0, w1);
    }
  }

  // ---- rgb staging, deep MLP: 5808 int4 = 11*512 + 176. Issue all loads
  // back-to-back into registers (static indices), then convert + LDS write.
  const int4* src4 = (const int4*)(rgb + (size_t)b * 88 * RGB_W);
  int4 r[11];
  #pragma unroll
  for (int it = 0; it < 11; ++it) r[it] = src4[tid + it * 512];
  int4 rt;
  const bool tail = (tid < 176);
  if (tail) rt = src4[5632 + tid];
  #pragma unroll
  for (int it = 0; it < 11; ++it) {
    const int i = tid + it * 512;
    const int e = i * 4, row = e / RGB_W, col = e - row * RGB_W;
    uint2 p;
    p.x = pack2((float)r[it].x * (1.f/255.f), (float)r[it].y * (1.f/255.f));
    p.y = pack2((float)r[it].z * (1.f/255.f), (float)r[it].w * (1.f/255.f));
    *(uint2*)&rgbL[row * LDR + col] = p;
  }
  if (tail) {
    const int i = 5632 + tid;
    const int e = i * 4, row = e / RGB_W, col = e - row * RGB_W;
    uint2 p;
    p.x = pack2((float)rt.x * (1.f/255.f), (float)rt.y * (1.f/255.f));
    p.y = pack2((float)rt.z * (1.f/255.f), (float)rt.w * (1.f/255.f));
    *(uint2*)&rgbL[row * LDR + col] = p;
  }
  __syncthreads();

  // ---- MFMA: wave w owns patch rows w*16..w*16+15, full N=64, K=192.
  // K-slice k0 = ks*32+lg*8 is a multiple of 8 -> never crosses a ky row
  // (k mod 24 in {0,8,16}) -> A-frag is a contiguous 16B slice of the image.
  const int p = w * 16 + lr;
  const int pe = p > 120 ? 120 : p;          // pad rows duplicate row 120
  const int oy = pe / 11, ox = pe - oy * 11;
  f32x4 acc[4] = {};
  #pragma unroll
  for (int ks = 0; ks < 6; ++ks) {
    const int k0 = ks * 32 + lg * 8;
    const int ky = k0 / 24, km = k0 - ky * 24;
    const bf16x8 a = *(const bf16x8*)&rgbL[(oy * 8 + ky) * LDR + ox * 24 + km];
    #pragma unroll
    for (int ni = 0; ni < 4; ++ni) {
      const bf16x8 bb = *(const bf16x8*)&BtL[(ni * 16 + lr) * LDB + k0];
      acc[ni] = __builtin_amdgcn_mfma_f32_16x16x32_bf16(a, bb, acc[ni], 0, 0, 0);
    }
  }
  __syncthreads();                           // rgbL reads done before aliasing

  // ---- epilogue: +bias, relu (+0 kills -0), store global + LDS bits
  float bias[4];
  #pragma unroll
  for (int ni = 0; ni < 4; ++ni) bias[ni] = bc[ni * 16 + lr];
  float* outB = out + (size_t)b * NPOS * NCH;
  #pragma unroll
  for (int rr = 0; rr < 4; ++rr) {
    const int ps = w * 16 + lg * 4 + rr;
    if (ps < NPOS) {
      #pragma unroll
      for (int ni = 0; ni < 4; ++ni) {
        const float v = fmaxf(acc[ni][rr] + bias[ni], 0.f) + 0.f;
        outB[ps * NCH + ni * 16 + lr] = v;
        fbits[ps * FST + ni * 16 + lr] = __float_as_uint(v);
      }
    }
  }
  __syncthreads();

  // ---- per-row signature (own-row hash, no atomics)
  if (tid < NPOS) {
    const uint4* fr = (const uint4*)&fbits[tid * FST];
    unsigned h = 0;
    #pragma unroll
    for (int q = 0; q < 16; ++q) {
      const uint4 v = fr[q];
      h ^= (v.x ^ (v.x >> 15)) * ((8u*q + 1u) * 0x9E3779B9u);
      h ^= (v.y ^ (v.y >> 15)) * ((8u*q + 3u) * 0x9E3779B9u);
      h ^= (v.z ^ (v.z >> 15)) * ((8u*q + 5u) * 0x9E3779B9u);
      h ^= (v.w ^ (v.w >> 15)) * ((8u*q + 7u) * 0x9E3779B9u);
    }
    sig[tid] = h;
  }
  __syncthreads();

  // ---- counts via signature match (exact verify on collision, ~never taken)
  int cnt = 0x7fffffff;
  if (tid < NPOS) {
    const unsigned si = sig[tid];
    int m = 0;
    for (int j = 0; j < NPOS; ++j) m += (sig[j] == si) ? 1 : 0;
    cnt = 1;
    if (m > 1) {
      cnt = 0;
      for (int j = 0; j < NPOS; ++j) {
        if (sig[j] == si) {
          int eq = 1;
          for (int c = 0; c < NCH; ++c) eq &= (fbits[tid*FST + c] == fbits[j*FST + c]);
          cnt += eq;
        }
      }
    }
    counts[tid] = cnt;
  }
  __syncthreads();

  // ---- kmin (block reduce over 8 waves)
  int km_ = cnt;
  #pragma unroll
  for (int off = 1; off < 64; off <<= 1) km_ = min(km_, __shfl_xor(km_, off, 64));
  if (lane == 0) redi[w] = km_;
  __syncthreads();
  int kmin = redi[0];
  #pragma unroll
  for (int q = 1; q < 8; ++q) kmin = min(kmin, redi[q]);

  // ---- allow rule: cum[c_i] = #{j: counts[j] <= c_i}; parallel, no histogram
  float wv = 0.f;
  if (tid < NPOS) {
    int cum = 0;
    for (int j = 0; j < NPOS; ++j) cum += (counts[j] <= cnt) ? 1 : 0;
    if (cum <= 36 || cnt == kmin) wv = 1.f / (float)cnt;   // K = int(0.3*121)
  }
  float s = wv;
  #pragma unroll
  for (int off = 1; off < 64; off <<= 1) s += __shfl_xor(s, off, 64);
  if (lane == 0) redf[w] = s;
  __syncthreads();
  float Z = redf[0];
  #pragma unroll
  for (int q = 1; q < 8; ++q) Z += redf[q];
  if (tid < NPOS) gout[(size_t)b * NPOS + tid] = wv / Z;
}

extern "C" void kernel_launch(void* const* d_in, const int* in_sizes, int n_in,
                              void* d_out, int out_size, void* d_ws, size_t ws_size,
                              hipStream_t stream) {
  const int*   rgb = (const int*)d_in[0];
  const float* Wc  = (const float*)d_in[1];
  const float* bc  = (const float*)d_in[2];
  float* out   = (float*)d_out;                        // vis_op: 30976 x 64
  float* guide = out + (size_t)NPATCH * NCH;           // guidance: 256 x 121

  fused<<<B_SZ, 512, 0, stream>>>(rgb, Wc, bc, out, guide);
}